// Round 15
// baseline (208.498 us; speedup 1.0000x reference)
//
#include <hip/hip_runtime.h>
#include <hip/hip_bf16.h>
#include <math.h>

#define DD 256
#define LN_EPS 1e-5f
#define BKT 128   // fixed bucket slots per destination node

typedef unsigned short u16;
typedef __attribute__((ext_vector_type(8))) short short8;
typedef __attribute__((ext_vector_type(4))) float floatx4;

__device__ __forceinline__ u16 f2b(float f) {
    __hip_bfloat16 h = __float2bfloat16(f);
    return *reinterpret_cast<u16*>(&h);
}
__device__ __forceinline__ float b2f(unsigned int u) {
    union { unsigned int i; float f; } x;
    x.i = u << 16;
    return x.f;
}

// ---------------- k_all: scatter | weight transpose+bf16 | LN1 (one launch) ----------------
// All three are mutually independent; the ~50us atomic-bound scatter shadows the prep.
// cnt must be pre-zeroed (hipMemsetAsync).

__global__ void __launch_bounds__(256) k_all(
    const int* __restrict__ src, const int* __restrict__ dst, int E_,
    int* __restrict__ cnt, int* __restrict__ bkt,
    const float* __restrict__ Wq, const float* __restrict__ Wk,
    const float* __restrict__ Wv, const float* __restrict__ Wo,
    u16* __restrict__ Wt,
    const float* __restrict__ x, const float* __restrict__ g1, const float* __restrict__ b1,
    int N_, u16* __restrict__ xn, int fb) {
    __shared__ float tile[64][65];
    int b = blockIdx.x;
    int t = threadIdx.x;

    if (b < fb) {                       // edge scatter (plain device atomics, many blocks)
        int e = b * 256 + t;
        if (e >= E_) return;
        int d = dst[e];
        int p = atomicAdd(&cnt[d], 1);
        if (p < BKT) bkt[(size_t)d * BKT + p] = src[e];
        return;
    }
    if (b < fb + 64) {                  // weight transpose + bf16 convert
        int bb = b - fb;
        int k0 = (bb & 3) * 64;
        int n0 = (bb >> 2) * 64;
        int sel = n0 >> 8;
        const float* W = (sel == 0) ? Wq : (sel == 1) ? Wk : (sel == 2) ? Wv : Wo;
        int ncol0 = n0 & 255;
#pragma unroll
        for (int p = 0; p < 16; p++) {
            int kk = p * 4 + (t >> 6);
            int nn = t & 63;
            tile[kk][nn] = W[(size_t)(k0 + kk) * DD + ncol0 + nn];
        }
        __syncthreads();
#pragma unroll
        for (int p = 0; p < 16; p++) {
            int nn = p * 4 + (t >> 6);
            int kk = t & 63;
            Wt[(size_t)(n0 + nn) * DD + k0 + kk] = f2b(tile[kk][nn]);
        }
        return;
    }
    // LN1: wave per node
    int lane = t & 63;
    int node = (b - fb - 64) * 4 + (t >> 6);
    if (node >= N_) return;
    size_t base = (size_t)node * DD + lane * 4;
    float4 xv = *(const float4*)&x[base];
    float s = xv.x + xv.y + xv.z + xv.w;
    s += __shfl_xor(s, 1); s += __shfl_xor(s, 2); s += __shfl_xor(s, 4);
    s += __shfl_xor(s, 8); s += __shfl_xor(s, 16); s += __shfl_xor(s, 32);
    float mean = s * (1.f / DD);
    float d0 = xv.x - mean, d1 = xv.y - mean, d2 = xv.z - mean, d3 = xv.w - mean;
    float v = d0 * d0 + d1 * d1 + d2 * d2 + d3 * d3;
    v += __shfl_xor(v, 1); v += __shfl_xor(v, 2); v += __shfl_xor(v, 4);
    v += __shfl_xor(v, 8); v += __shfl_xor(v, 16); v += __shfl_xor(v, 32);
    float rstd = rsqrtf(v * (1.f / DD) + LN_EPS);
    float4 gv = *(const float4*)&g1[lane * 4];
    float4 bv = *(const float4*)&b1[lane * 4];
    uint2 o;
    o.x = (unsigned)f2b(d0 * rstd * gv.x + bv.x) | ((unsigned)f2b(d1 * rstd * gv.y + bv.y) << 16);
    o.y = (unsigned)f2b(d2 * rstd * gv.z + bv.z) | ((unsigned)f2b(d3 * rstd * gv.w + bv.w) << 16);
    *(uint2*)&xn[base] = o;
}

// ---------------- QKV GEMM: no-LDS direct-from-L2 MFMA ----------------
// kv layout (bf16): kv[node*512 + lane*8 + j], lane = h*16+li: k dims at j=0..3, v at j=4..7.

__global__ void __launch_bounds__(256) k_qkv(
    const u16* __restrict__ xn, const u16* __restrict__ Wt,
    const float* __restrict__ bq, const float* __restrict__ bk, const float* __restrict__ bv,
    int N_, float* __restrict__ q, u16* __restrict__ kv) {
    int t = threadIdx.x;
    int w = t >> 6, lane = t & 63;
    int li = lane & 15, quad = lane >> 4;
    int m0 = blockIdx.x * 32;
    int ncol0 = blockIdx.y * 384 + w * 96;

    floatx4 acc[2][6];
#pragma unroll
    for (int mi = 0; mi < 2; mi++)
#pragma unroll
        for (int nf = 0; nf < 6; nf++) acc[mi][nf] = (floatx4){0.f, 0.f, 0.f, 0.f};

    int r0 = m0 + li;      if (r0 > N_ - 1) r0 = N_ - 1;
    int r1 = m0 + 16 + li; if (r1 > N_ - 1) r1 = N_ - 1;
    const u16* A0 = xn + (size_t)r0 * DD;
    const u16* A1 = xn + (size_t)r1 * DD;
    const u16* B0 = Wt + (size_t)(ncol0 + li) * DD;

#pragma unroll 2
    for (int kk = 0; kk < 8; kk++) {
        int ko = kk * 32 + quad * 8;
        short8 a0 = *(const short8*)&A0[ko];
        short8 a1 = *(const short8*)&A1[ko];
#pragma unroll
        for (int nf = 0; nf < 6; nf++) {
            short8 bfrag = *(const short8*)&B0[(size_t)nf * 16 * DD + ko];
            acc[0][nf] = __builtin_amdgcn_mfma_f32_16x16x32_bf16(a0, bfrag, acc[0][nf], 0, 0, 0);
            acc[1][nf] = __builtin_amdgcn_mfma_f32_16x16x32_bf16(a1, bfrag, acc[1][nf], 0, 0, 0);
        }
    }

#pragma unroll
    for (int nf = 0; nf < 6; nf++) {
        int ncol = ncol0 + nf * 16 + li;
        int kind, c;
        float bias;
        if (ncol < 256)      { kind = 0; c = ncol;       bias = bq[c]; }
        else if (ncol < 512) { kind = 1; c = ncol - 256; bias = bk[c]; }
        else                 { kind = 2; c = ncol - 512; bias = bv[c]; }
#pragma unroll
        for (int mi = 0; mi < 2; mi++) {
#pragma unroll
            for (int r = 0; r < 4; r++) {
                int row = m0 + mi * 16 + quad * 4 + r;
                if (row >= N_) continue;
                float val = acc[mi][nf][r] + bias;
                if (kind == 0) {
                    q[(size_t)row * DD + c] = val * 0.125f;  // fold 1/sqrt(64)
                } else {
                    size_t idx = (size_t)row * 512 + (c >> 6) * 128 + ((c & 63) >> 2) * 8 + (c & 3)
                               + (kind == 2 ? 4 : 0);
                    kv[idx] = f2b(val);
                }
            }
        }
    }
}

// ---------------- fused attention + out-GEMM: 8 nodes/block, 1250 blocks ----------------
// Phase 1: wave w handles nodes m0+w*2, m0+w*2+1 (full kv row per edge across 64 lanes,
//   ILP-8). agg -> LDS bf16. 2x the resident waves of the 16-node variant (grid was the
//   occupancy limiter at 625 blocks).
// Phase 2: 8-row out-GEMM from LDS A-fragments (li<8 valid, rest zero), Wt from L2,
//   LN2 + relu + residual epilogue.

__global__ void __launch_bounds__(256) k_ao(
    const float* __restrict__ q, const u16* __restrict__ kv,
    const int* __restrict__ cnt, const int* __restrict__ bkt,
    const u16* __restrict__ Wt, const float* __restrict__ bo,
    const float* __restrict__ g2, const float* __restrict__ b2,
    const float* __restrict__ x, int N_, float* __restrict__ out) {
    __shared__ u16 ags[8][260];
    __shared__ float wsum[4][16];
    __shared__ float wvar[4][16];
    int t = threadIdx.x;
    int w = t >> 6, lane = t & 63;
    int m0 = blockIdx.x * 8;

    // ---- phase 1: attention (2 nodes per wave) ----
    for (int ni = 0; ni < 2; ni++) {
        int row = w * 2 + ni;
        int node = m0 + row;
        int deg = 0;
        if (node < N_) { deg = cnt[node]; if (deg > BKT) deg = BKT; }
        if (deg == 0) {
            uint2 z; z.x = 0u; z.y = 0u;
            *(uint2*)&ags[row][lane * 4] = z;
            continue;
        }
        const int* eb = bkt + (size_t)node * BKT;
        int last = deg - 1;
        float4 qv = *(const float4*)&q[(size_t)node * DD + lane * 4];
        size_t kvoff = (size_t)lane * 8;

        float l = 0.f, ax = 0.f, ay = 0.f, az = 0.f, aw = 0.f;
        int src[8];
#pragma unroll
        for (int d = 0; d < 8; d++) src[d] = eb[d <= last ? d : last];

        for (int e = 0; e < deg; e += 8) {
            uint4 p[8];
#pragma unroll
            for (int d = 0; d < 8; d++) p[d] = *(const uint4*)&kv[(size_t)src[d] * 512 + kvoff];
#pragma unroll
            for (int d = 0; d < 8; d++) {
                int i = e + 8 + d;
                src[d] = eb[i <= last ? i : last];
            }
#pragma unroll
            for (int d = 0; d < 8; d++) {
                bool valid = (e + d) < deg;
                float s = qv.x * b2f(p[d].x & 0xffff) + qv.y * b2f(p[d].x >> 16)
                        + qv.z * b2f(p[d].y & 0xffff) + qv.w * b2f(p[d].y >> 16);
                s += __shfl_xor(s, 1); s += __shfl_xor(s, 2);
                s += __shfl_xor(s, 4); s += __shfl_xor(s, 8);   // sum over 16-lane head group
                float pe = valid ? __expf(s) : 0.f;
                l += pe;
                ax += pe * b2f(p[d].z & 0xffff);
                ay += pe * b2f(p[d].z >> 16);
                az += pe * b2f(p[d].w & 0xffff);
                aw += pe * b2f(p[d].w >> 16);
            }
        }
        float invl = 1.f / l;
        uint2 o;
        o.x = (unsigned)f2b(ax * invl) | ((unsigned)f2b(ay * invl) << 16);
        o.y = (unsigned)f2b(az * invl) | ((unsigned)f2b(aw * invl) << 16);
        *(uint2*)&ags[row][lane * 4] = o;   // col = h*64+li*4 = lane*4
    }
    __syncthreads();

    // ---- phase 2: out GEMM (8 valid rows), cols w*64..+64 ----
    int li = lane & 15, quad = lane >> 4;
    floatx4 acc[4];
#pragma unroll
    for (int nf = 0; nf < 4; nf++) acc[nf] = (floatx4){0.f, 0.f, 0.f, 0.f};
    const u16* B0 = Wt + (size_t)(768 + w * 64 + li) * DD;
    short8 zfrag = (short8){0, 0, 0, 0, 0, 0, 0, 0};

#pragma unroll 2
    for (int kk = 0; kk < 8; kk++) {
        int ko = kk * 32 + quad * 8;
        short8 a = (li < 8) ? *(const short8*)&ags[li][ko] : zfrag;
#pragma unroll
        for (int nf = 0; nf < 4; nf++) {
            short8 bfrag = *(const short8*)&B0[(size_t)nf * 16 * DD + ko];
            acc[nf] = __builtin_amdgcn_mfma_f32_16x16x32_bf16(a, bfrag, acc[nf], 0, 0, 0);
        }
    }

#pragma unroll
    for (int nf = 0; nf < 4; nf++) {
        float bb = bo[w * 64 + nf * 16 + li];
#pragma unroll
        for (int r = 0; r < 4; r++) acc[nf][r] += bb;
    }

    // LN2: per-row partials over this wave's 64 cols, then cross-wave via LDS
#pragma unroll
    for (int r = 0; r < 4; r++) {
        float s = acc[0][r] + acc[1][r] + acc[2][r] + acc[3][r];
        s += __shfl_xor(s, 1); s += __shfl_xor(s, 2);
        s += __shfl_xor(s, 4); s += __shfl_xor(s, 8);
        if (li == 0) wsum[w][quad * 4 + r] = s;
    }
    __syncthreads();
    float mean[4];
#pragma unroll
    for (int r = 0; r < 4; r++) {
        int rl = quad * 4 + r;
        mean[r] = (wsum[0][rl] + wsum[1][rl] + wsum[2][rl] + wsum[3][rl]) * (1.f / DD);
    }
#pragma unroll
    for (int r = 0; r < 4; r++) {
        float vs = 0.f;
#pragma unroll
        for (int nf = 0; nf < 4; nf++) {
            float d = acc[nf][r] - mean[r];
            vs += d * d;
        }
        vs += __shfl_xor(vs, 1); vs += __shfl_xor(vs, 2);
        vs += __shfl_xor(vs, 4); vs += __shfl_xor(vs, 8);
        if (li == 0) wvar[w][quad * 4 + r] = vs;
    }
    __syncthreads();
    float rstd[4];
#pragma unroll
    for (int r = 0; r < 4; r++) {
        int rl = quad * 4 + r;
        rstd[r] = rsqrtf((wvar[0][rl] + wvar[1][rl] + wvar[2][rl] + wvar[3][rl]) * (1.f / DD) + LN_EPS);
    }

#pragma unroll
    for (int nf = 0; nf < 4; nf++) {
        int col = w * 64 + nf * 16 + li;
        float gv = g2[col], bv2 = b2[col];
#pragma unroll
        for (int r = 0; r < 4; r++) {
            int rtile = quad * 4 + r;
            if (rtile >= 8) continue;          // zero-padded rows
            int row = m0 + rtile;
            if (row >= N_) continue;
            float y = (acc[nf][r] - mean[r]) * rstd[r] * gv + bv2;
            y = fmaxf(y, 0.f);
            out[(size_t)row * DD + col] = x[(size_t)row * DD + col] + y;
        }
    }
}

// ---------------- launch ----------------

extern "C" void kernel_launch(void* const* d_in, const int* in_sizes, int n_in,
                              void* d_out, int out_size, void* d_ws, size_t ws_size,
                              hipStream_t stream) {
    const float* x  = (const float*)d_in[0];
    const int*   ei = (const int*)d_in[1];
    const float* g1 = (const float*)d_in[2];
    const float* b1 = (const float*)d_in[3];
    const float* g2 = (const float*)d_in[4];
    const float* b2 = (const float*)d_in[5];
    const float* Wq = (const float*)d_in[6];
    const float* bq = (const float*)d_in[7];
    const float* Wk = (const float*)d_in[8];
    const float* bk = (const float*)d_in[9];
    const float* Wv = (const float*)d_in[10];
    const float* bv = (const float*)d_in[11];
    const float* Wo = (const float*)d_in[12];
    const float* bo = (const float*)d_in[13];
    float* out = (float*)d_out;

    int N_ = in_sizes[0] / DD;
    int E_ = in_sizes[1] / 2;
    const int* srcp = ei;
    const int* dstp = ei + E_;

    char* w = (char*)d_ws;
    float* q   = (float*)w;  w += (size_t)N_ * DD * 4;
    u16* xn    = (u16*)w;    w += (size_t)N_ * DD * 2;
    u16* kv    = (u16*)w;    w += (size_t)N_ * 512 * 2;
    u16* Wt    = (u16*)w;    w += (size_t)1024 * DD * 2;
    int* cnt   = (int*)w;    w += (size_t)N_ * 4;
    int* bkt   = (int*)w;    w += (size_t)N_ * BKT * 4;

    hipMemsetAsync(cnt, 0, (size_t)N_ * 4, stream);

    int fb = (E_ + 255) / 256;
    int all_blocks = fb + 64 + (N_ + 3) / 4;
    int nxb = (N_ + 31) / 32;

    k_all<<<all_blocks, 256, 0, stream>>>(srcp, dstp, E_, cnt, bkt,
                                          Wq, Wk, Wv, Wo, Wt, x, g1, b1, N_, xn, fb);
    k_qkv<<<dim3(nxb, 2), 256, 0, stream>>>(xn, Wt, bq, bk, bv, N_, q, kv);
    k_ao<<<(N_ + 7) / 8, 256, 0, stream>>>(q, kv, cnt, bkt, Wt, bo, g2, b2, x, N_, out);
}

// Round 16
// 197.148 us; speedup vs baseline: 1.0576x; 1.0576x over previous
//
#include <hip/hip_runtime.h>
#include <hip/hip_bf16.h>
#include <math.h>

#define DD 256
#define LN_EPS 1e-5f
#define BKT 128   // fixed bucket slots per destination node

typedef unsigned short u16;
typedef __attribute__((ext_vector_type(8))) short short8;
typedef __attribute__((ext_vector_type(4))) float floatx4;

__device__ __forceinline__ u16 f2b(float f) {
    __hip_bfloat16 h = __float2bfloat16(f);
    return *reinterpret_cast<u16*>(&h);
}
__device__ __forceinline__ float b2f(unsigned int u) {
    union { unsigned int i; float f; } x;
    x.i = u << 16;
    return x.f;
}

// ---------------- fused preamble: cnt-zero | weight transpose+bf16 | LN1 ----------------
// cnt is PACKED: 2 destination counters per u32 (u16 fields; deg <= ~70 << 65535).

__global__ void __launch_bounds__(256) k_pre(
    const float* __restrict__ Wq, const float* __restrict__ Wk,
    const float* __restrict__ Wv, const float* __restrict__ Wo,
    u16* __restrict__ Wt,
    const float* __restrict__ x, const float* __restrict__ g1, const float* __restrict__ b1,
    int N_, u16* __restrict__ xn, unsigned* __restrict__ cnt, int npair, int zb) {
    __shared__ float tile[64][65];
    int b = blockIdx.x;
    int t = threadIdx.x;

    if (b < zb) {                       // zero packed bucket counters
        int i = b * 256 + t;
        if (i < npair) cnt[i] = 0u;
        return;
    }
    if (b < zb + 64) {                  // weight transpose + bf16 convert
        int bb = b - zb;
        int k0 = (bb & 3) * 64;
        int n0 = (bb >> 2) * 64;
        int sel = n0 >> 8;
        const float* W = (sel == 0) ? Wq : (sel == 1) ? Wk : (sel == 2) ? Wv : Wo;
        int ncol0 = n0 & 255;
#pragma unroll
        for (int p = 0; p < 16; p++) {
            int kk = p * 4 + (t >> 6);
            int nn = t & 63;
            tile[kk][nn] = W[(size_t)(k0 + kk) * DD + ncol0 + nn];
        }
        __syncthreads();
#pragma unroll
        for (int p = 0; p < 16; p++) {
            int nn = p * 4 + (t >> 6);
            int kk = t & 63;
            Wt[(size_t)(n0 + nn) * DD + k0 + kk] = f2b(tile[kk][nn]);
        }
        return;
    }
    // LN1: wave per node
    int lane = t & 63;
    int node = (b - zb - 64) * 4 + (t >> 6);
    if (node >= N_) return;
    size_t base = (size_t)node * DD + lane * 4;
    float4 xv = *(const float4*)&x[base];
    float s = xv.x + xv.y + xv.z + xv.w;
    s += __shfl_xor(s, 1); s += __shfl_xor(s, 2); s += __shfl_xor(s, 4);
    s += __shfl_xor(s, 8); s += __shfl_xor(s, 16); s += __shfl_xor(s, 32);
    float mean = s * (1.f / DD);
    float d0 = xv.x - mean, d1 = xv.y - mean, d2 = xv.z - mean, d3 = xv.w - mean;
    float v = d0 * d0 + d1 * d1 + d2 * d2 + d3 * d3;
    v += __shfl_xor(v, 1); v += __shfl_xor(v, 2); v += __shfl_xor(v, 4);
    v += __shfl_xor(v, 8); v += __shfl_xor(v, 16); v += __shfl_xor(v, 32);
    float rstd = rsqrtf(v * (1.f / DD) + LN_EPS);
    float4 gv = *(const float4*)&g1[lane * 4];
    float4 bv = *(const float4*)&b1[lane * 4];
    uint2 o;
    o.x = (unsigned)f2b(d0 * rstd * gv.x + bv.x) | ((unsigned)f2b(d1 * rstd * gv.y + bv.y) << 16);
    o.y = (unsigned)f2b(d2 * rstd * gv.z + bv.z) | ((unsigned)f2b(d3 * rstd * gv.w + bv.w) << 16);
    *(uint2*)&xn[base] = o;
}

// ---------------- merged: bucket scatter (packed counters) | QKV GEMM ----------------
// kv layout (bf16): kv[node*512 + lane*8 + j], lane = h*16+li: k dims at j=0..3, v at j=4..7.

__global__ void __launch_bounds__(256) k_mid(
    const int* __restrict__ src, const int* __restrict__ dst, int E_,
    unsigned* __restrict__ cnt, int* __restrict__ bkt,
    const u16* __restrict__ xn, const u16* __restrict__ Wt,
    const float* __restrict__ bq, const float* __restrict__ bk, const float* __restrict__ bv,
    int N_, float* __restrict__ q, u16* __restrict__ kv, int fb) {
    int b = blockIdx.x;
    int t = threadIdx.x;

    if (b < fb) {                       // edge scatter: one packed atomic per edge
        int e = b * 256 + t;
        if (e >= E_) return;
        int d = dst[e];
        unsigned inc = (d & 1) ? 0x10000u : 1u;
        unsigned old = atomicAdd(&cnt[d >> 1], inc);
        unsigned p = (d & 1) ? (old >> 16) : (old & 0xffffu);
        if (p < BKT) bkt[(size_t)d * BKT + p] = src[e];
        return;
    }

    // QKV GEMM (no-LDS, direct-from-L2 MFMA fragments)
    int bq_ = b - fb;
    int nxb = (N_ + 31) / 32;
    int bx = bq_ % nxb, by = bq_ / nxb;
    int w = t >> 6, lane = t & 63;
    int li = lane & 15, quad = lane >> 4;
    int m0 = bx * 32;
    int ncol0 = by * 384 + w * 96;

    floatx4 acc[2][6];
#pragma unroll
    for (int mi = 0; mi < 2; mi++)
#pragma unroll
        for (int nf = 0; nf < 6; nf++) acc[mi][nf] = (floatx4){0.f, 0.f, 0.f, 0.f};

    int r0 = m0 + li;      if (r0 > N_ - 1) r0 = N_ - 1;
    int r1 = m0 + 16 + li; if (r1 > N_ - 1) r1 = N_ - 1;
    const u16* A0 = xn + (size_t)r0 * DD;
    const u16* A1 = xn + (size_t)r1 * DD;
    const u16* B0 = Wt + (size_t)(ncol0 + li) * DD;

#pragma unroll 2
    for (int kk = 0; kk < 8; kk++) {
        int ko = kk * 32 + quad * 8;
        short8 a0 = *(const short8*)&A0[ko];
        short8 a1 = *(const short8*)&A1[ko];
#pragma unroll
        for (int nf = 0; nf < 6; nf++) {
            short8 bfrag = *(const short8*)&B0[(size_t)nf * 16 * DD + ko];
            acc[0][nf] = __builtin_amdgcn_mfma_f32_16x16x32_bf16(a0, bfrag, acc[0][nf], 0, 0, 0);
            acc[1][nf] = __builtin_amdgcn_mfma_f32_16x16x32_bf16(a1, bfrag, acc[1][nf], 0, 0, 0);
        }
    }

#pragma unroll
    for (int nf = 0; nf < 6; nf++) {
        int ncol = ncol0 + nf * 16 + li;
        int kind, c;
        float bias;
        if (ncol < 256)      { kind = 0; c = ncol;       bias = bq[c]; }
        else if (ncol < 512) { kind = 1; c = ncol - 256; bias = bk[c]; }
        else                 { kind = 2; c = ncol - 512; bias = bv[c]; }
#pragma unroll
        for (int mi = 0; mi < 2; mi++) {
#pragma unroll
            for (int r = 0; r < 4; r++) {
                int row = m0 + mi * 16 + quad * 4 + r;
                if (row >= N_) continue;
                float val = acc[mi][nf][r] + bias;
                if (kind == 0) {
                    q[(size_t)row * DD + c] = val * 0.125f;  // fold 1/sqrt(64)
                } else {
                    size_t idx = (size_t)row * 512 + (c >> 6) * 128 + ((c & 63) >> 2) * 8 + (c & 3)
                               + (kind == 2 ? 4 : 0);
                    kv[idx] = f2b(val);
                }
            }
        }
    }
}

// ---------------- merged attention + out-GEMM: 16 nodes/block (R11-proven) ----------------
// Phase 1: wave w does nodes m0+w*4..+4, ALL heads per edge (lane = h*16+li covers
//   the full kv row: one 1KB gather per edge across the wave). agg -> LDS (bf16).
// Phase 2: out-GEMM rows from LDS A-fragments + Wt from L2, LN2+relu+residual.

__global__ void __launch_bounds__(256) k_ao(
    const float* __restrict__ q, const u16* __restrict__ kv,
    const unsigned* __restrict__ cnt, const int* __restrict__ bkt,
    const u16* __restrict__ Wt, const float* __restrict__ bo,
    const float* __restrict__ g2, const float* __restrict__ b2,
    const float* __restrict__ x, int N_, float* __restrict__ out) {
    __shared__ u16 ags[16][260];
    __shared__ float wsum[4][16];
    __shared__ float wvar[4][16];
    int t = threadIdx.x;
    int w = t >> 6, lane = t & 63;
    int m0 = blockIdx.x * 16;

    // ---- phase 1: attention ----
    for (int ni = 0; ni < 4; ni++) {
        int node = m0 + w * 4 + ni;
        int row = w * 4 + ni;
        int deg = 0;
        if (node < N_) {
            unsigned uc = cnt[node >> 1];
            deg = (node & 1) ? (int)(uc >> 16) : (int)(uc & 0xffffu);
            if (deg > BKT) deg = BKT;
        }
        if (deg == 0) {
            uint2 z; z.x = 0u; z.y = 0u;
            *(uint2*)&ags[row][lane * 4] = z;
            continue;
        }
        const int* eb = bkt + (size_t)node * BKT;
        int last = deg - 1;
        float4 qv = *(const float4*)&q[(size_t)node * DD + lane * 4];
        size_t kvoff = (size_t)lane * 8;

        float l = 0.f, ax = 0.f, ay = 0.f, az = 0.f, aw = 0.f;
        int src[8];
#pragma unroll
        for (int d = 0; d < 8; d++) src[d] = eb[d <= last ? d : last];

        for (int e = 0; e < deg; e += 8) {
            uint4 p[8];
#pragma unroll
            for (int d = 0; d < 8; d++) p[d] = *(const uint4*)&kv[(size_t)src[d] * 512 + kvoff];
#pragma unroll
            for (int d = 0; d < 8; d++) {
                int i = e + 8 + d;
                src[d] = eb[i <= last ? i : last];
            }
#pragma unroll
            for (int d = 0; d < 8; d++) {
                bool valid = (e + d) < deg;
                float s = qv.x * b2f(p[d].x & 0xffff) + qv.y * b2f(p[d].x >> 16)
                        + qv.z * b2f(p[d].y & 0xffff) + qv.w * b2f(p[d].y >> 16);
                s += __shfl_xor(s, 1); s += __shfl_xor(s, 2);
                s += __shfl_xor(s, 4); s += __shfl_xor(s, 8);   // 16-lane head group
                float pe = valid ? __expf(s) : 0.f;
                l += pe;
                ax += pe * b2f(p[d].z & 0xffff);
                ay += pe * b2f(p[d].z >> 16);
                az += pe * b2f(p[d].w & 0xffff);
                aw += pe * b2f(p[d].w >> 16);
            }
        }
        float invl = 1.f / l;
        uint2 o;
        o.x = (unsigned)f2b(ax * invl) | ((unsigned)f2b(ay * invl) << 16);
        o.y = (unsigned)f2b(az * invl) | ((unsigned)f2b(aw * invl) << 16);
        *(uint2*)&ags[row][lane * 4] = o;   // col = h*64+li*4 = lane*4
    }
    __syncthreads();

    // ---- phase 2: out GEMM (16 rows), cols w*64..+64 ----
    int li = lane & 15, quad = lane >> 4;
    floatx4 acc[4];
#pragma unroll
    for (int nf = 0; nf < 4; nf++) acc[nf] = (floatx4){0.f, 0.f, 0.f, 0.f};
    const u16* B0 = Wt + (size_t)(768 + w * 64 + li) * DD;

#pragma unroll 2
    for (int kk = 0; kk < 8; kk++) {
        int ko = kk * 32 + quad * 8;
        short8 a = *(const short8*)&ags[li][ko];
#pragma unroll
        for (int nf = 0; nf < 4; nf++) {
            short8 bfrag = *(const short8*)&B0[(size_t)nf * 16 * DD + ko];
            acc[nf] = __builtin_amdgcn_mfma_f32_16x16x32_bf16(a, bfrag, acc[nf], 0, 0, 0);
        }
    }

#pragma unroll
    for (int nf = 0; nf < 4; nf++) {
        float bb = bo[w * 64 + nf * 16 + li];
#pragma unroll
        for (int r = 0; r < 4; r++) acc[nf][r] += bb;
    }

    // LN2: per-row partials over this wave's 64 cols, then cross-wave via LDS
#pragma unroll
    for (int r = 0; r < 4; r++) {
        float s = acc[0][r] + acc[1][r] + acc[2][r] + acc[3][r];
        s += __shfl_xor(s, 1); s += __shfl_xor(s, 2);
        s += __shfl_xor(s, 4); s += __shfl_xor(s, 8);
        if (li == 0) wsum[w][quad * 4 + r] = s;
    }
    __syncthreads();
    float mean[4];
#pragma unroll
    for (int r = 0; r < 4; r++) {
        int rl = quad * 4 + r;
        mean[r] = (wsum[0][rl] + wsum[1][rl] + wsum[2][rl] + wsum[3][rl]) * (1.f / DD);
    }
#pragma unroll
    for (int r = 0; r < 4; r++) {
        float vs = 0.f;
#pragma unroll
        for (int nf = 0; nf < 4; nf++) {
            float d = acc[nf][r] - mean[r];
            vs += d * d;
        }
        vs += __shfl_xor(vs, 1); vs += __shfl_xor(vs, 2);
        vs += __shfl_xor(vs, 4); vs += __shfl_xor(vs, 8);
        if (li == 0) wvar[w][quad * 4 + r] = vs;
    }
    __syncthreads();
    float rstd[4];
#pragma unroll
    for (int r = 0; r < 4; r++) {
        int rl = quad * 4 + r;
        rstd[r] = rsqrtf((wvar[0][rl] + wvar[1][rl] + wvar[2][rl] + wvar[3][rl]) * (1.f / DD) + LN_EPS);
    }

#pragma unroll
    for (int nf = 0; nf < 4; nf++) {
        int col = w * 64 + nf * 16 + li;
        float gv = g2[col], bv2 = b2[col];
#pragma unroll
        for (int r = 0; r < 4; r++) {
            int row = m0 + quad * 4 + r;
            if (row >= N_) continue;
            float y = (acc[nf][r] - mean[r]) * rstd[r] * gv + bv2;
            y = fmaxf(y, 0.f);
            out[(size_t)row * DD + col] = x[(size_t)row * DD + col] + y;
        }
    }
}

// ---------------- launch ----------------

extern "C" void kernel_launch(void* const* d_in, const int* in_sizes, int n_in,
                              void* d_out, int out_size, void* d_ws, size_t ws_size,
                              hipStream_t stream) {
    const float* x  = (const float*)d_in[0];
    const int*   ei = (const int*)d_in[1];
    const float* g1 = (const float*)d_in[2];
    const float* b1 = (const float*)d_in[3];
    const float* g2 = (const float*)d_in[4];
    const float* b2 = (const float*)d_in[5];
    const float* Wq = (const float*)d_in[6];
    const float* bq = (const float*)d_in[7];
    const float* Wk = (const float*)d_in[8];
    const float* bk = (const float*)d_in[9];
    const float* Wv = (const float*)d_in[10];
    const float* bv = (const float*)d_in[11];
    const float* Wo = (const float*)d_in[12];
    const float* bo = (const float*)d_in[13];
    float* out = (float*)d_out;

    int N_ = in_sizes[0] / DD;
    int E_ = in_sizes[1] / 2;
    const int* srcp = ei;
    const int* dstp = ei + E_;

    char* w = (char*)d_ws;
    float* q   = (float*)w;  w += (size_t)N_ * DD * 4;
    u16* xn    = (u16*)w;    w += (size_t)N_ * DD * 2;
    u16* kv    = (u16*)w;    w += (size_t)N_ * 512 * 2;
    u16* Wt    = (u16*)w;    w += (size_t)1024 * DD * 2;
    unsigned* cnt = (unsigned*)w; w += (size_t)((N_ + 1) / 2 + 1) * 4;
    int* bkt   = (int*)w;    w += (size_t)N_ * BKT * 4;

    int npair = (N_ + 1) / 2;
    int zb = (npair + 255) / 256;
    int pre_blocks = zb + 64 + (N_ + 3) / 4;

    int fb = (E_ + 255) / 256;
    int nxb = (N_ + 31) / 32;
    int mid_blocks = fb + nxb * 2;

    k_pre<<<pre_blocks, 256, 0, stream>>>(Wq, Wk, Wv, Wo, Wt, x, g1, b1, N_, xn,
                                          cnt, npair, zb);
    k_mid<<<mid_blocks, 256, 0, stream>>>(srcp, dstp, E_, cnt, bkt,
                                          xn, Wt, bq, bk, bv, N_, q, kv, fb);
    k_ao<<<(N_ + 15) / 16, 256, 0, stream>>>(q, kv, cnt, bkt, Wt, bo, g2, b2, x, N_, out);
}